// Round 21
// baseline (102.238 us; speedup 1.0000x reference)
//
#include <hip/hip_runtime.h>
#include <hip/hip_bf16.h>

typedef float f32x4 __attribute__((ext_vector_type(4)));
typedef float f32x16 __attribute__((ext_vector_type(16)));
typedef __bf16 bf16x8 __attribute__((ext_vector_type(8)));
typedef unsigned short u16x8 __attribute__((ext_vector_type(8)));
typedef unsigned u32x4 __attribute__((ext_vector_type(4)));

#define NB 4
#define SL 2048
#define NH 16
#define HD 64
#define KBLK 64
#define PAD 72
#define NT 16            // q-tiles of 128

static __device__ __forceinline__ unsigned short f2bf(float f) {
    unsigned u = __builtin_bit_cast(unsigned, f);
    u += 0x7fffu + ((u >> 16) & 1u);
    return (unsigned short)(u >> 16);
}

static __device__ __forceinline__ unsigned pk2(float lo, float hi) {
    unsigned r;
    asm("v_cvt_pk_bf16_f32 %0, %1, %2" : "=v"(r) : "v"(lo), "v"(hi));
    return r;
}

// raw 2^x (args <= 8 here; -1e30 -> 0 as desired)
static __device__ __forceinline__ float fexp2(float x) {
    float r;
    asm("v_exp_f32 %0, %1" : "=v"(r) : "v"(x));
    return r;
}

// a' = [a.lo32 | b.lo32], b' = [a.hi32 | b.hi32]  (r7-proven semantics)
static __device__ __forceinline__ void pl32swap(unsigned& a, unsigned& b) {
    asm("v_permlane32_swap_b32 %0, %1" : "+v"(a), "+v"(b));
}

// ---- prologue: V fp32 [b][s][h][d] -> bf16 transposed [b][h][d][s] ----
__global__ void conv_v(const float* __restrict__ Vg, unsigned short* __restrict__ Vtb) {
    __shared__ unsigned short T[64 * PAD];
    const int tid = threadIdx.x;
    const int id  = blockIdx.x;
    const int st  = id & 31;
    const int bh  = id >> 5;
    const int s0  = st * 64;
    {
        const int sl = tid >> 2, c = (tid & 3) * 16;
        const float* src = Vg + ((size_t)((bh >> 4) * SL + s0 + sl) * NH + (bh & 15)) * HD + c;
        u16x8 a, b2;
        #pragma unroll
        for (int j = 0; j < 8; ++j) { a[j] = f2bf(src[j]); b2[j] = f2bf(src[8 + j]); }
        *(u16x8*)&T[sl * PAD + c]     = a;
        *(u16x8*)&T[sl * PAD + c + 8] = b2;
    }
    __syncthreads();
    {
        const int d = tid >> 2, sc = (tid & 3) * 16;
        u16x8 o0, o1;
        #pragma unroll
        for (int j = 0; j < 8; ++j) { o0[j] = T[(sc + j) * PAD + d]; o1[j] = T[(sc + 8 + j) * PAD + d]; }
        unsigned short* dst = Vtb + ((size_t)bh * HD + d) * SL + s0 + sc;
        *(u16x8*)dst       = o0;
        *(u16x8*)(dst + 8) = o1;
    }
}

// ---- main: 4 waves/block, 2 fi/wave of 32 q-rows, 32x32x16 MFMA,
//      stage-split fi processing (QK both -> softmax both -> PV both) ----
__global__ __launch_bounds__(256, 2)
void fattn_kernel(const float* __restrict__ Qg, const float* __restrict__ Kg,
                  const unsigned short* __restrict__ Vtb, float* __restrict__ Og)
{
    __shared__ unsigned short Klds[KBLK * PAD];
    __shared__ unsigned short Vlds[HD * PAD];

    const int tid  = threadIdx.x;
    const int w    = tid >> 6;          // 0..3
    const int lane = tid & 63;
    const int l31  = lane & 31;
    const int hi   = lane >> 5;

    const int bh   = blockIdx.x & 63;
    const int rawp = blockIdx.x >> 6;   // 0..7
    const int p    = (rawp < 4) ? rawp : 11 - rawp;
    const int b    = bh >> 4;
    const int h    = bh & 15;

    int qrows[2];
    qrows[0] = p * 128 + w * 32;              // tile p (short)
    qrows[1] = (NT - 1 - p) * 128 + w * 32;   // tile 15-p (long)
    const int tmax = 2 * (NT - 1 - p) + 1;

    const float QSCALE = 0.125f * 1.44269504088896f;  // (1/sqrt64)*log2(e)
    // Q-frag (B operand): lane holds Q[qf+l31][e = kk*16 + hi*8 + j]
    bf16x8 qfrag[2][4];
    #pragma unroll
    for (int fi = 0; fi < 2; ++fi) {
        const int q = qrows[fi] + l31;
        const float* qp = Qg + ((size_t)(b * SL + q) * NH + h) * HD + hi * 8;
        #pragma unroll
        for (int kk = 0; kk < 4; ++kk) {
            f32x4 a = *(const f32x4*)(qp + kk * 16);
            f32x4 b2 = *(const f32x4*)(qp + kk * 16 + 4);
            u16x8 t;
            #pragma unroll
            for (int j = 0; j < 4; ++j) { t[j] = f2bf(a[j] * QSCALE); t[4 + j] = f2bf(b2[j] * QSCALE); }
            qfrag[fi][kk] = __builtin_bit_cast(bf16x8, t);
        }
    }

    float m_run[2] = {-1e30f, -1e30f};
    float l_run[2] = {0.f, 0.f};   // per-lane partials, reduced at epilogue
    f32x16 oacc[2][2];             // [fi][dsub]
    #pragma unroll
    for (int fi = 0; fi < 2; ++fi)
        #pragma unroll
        for (int d = 0; d < 2; ++d)
            #pragma unroll
            for (int r = 0; r < 16; ++r) oacc[fi][d][r] = 0.f;

    const int srow = tid >> 2;          // 0..63
    const int scol = (tid & 3) * 16;    // 0..48
    const float* kgbase = Kg + ((size_t)b * SL * NH + h) * HD;
    const unsigned short* vbase = Vtb + (size_t)bh * HD * SL;

    f32x4 kf[4];
    #pragma unroll
    for (int j = 0; j < 4; ++j)
        kf[j] = *(const f32x4*)(kgbase + (size_t)srow * NH * HD + scol + j * 4);
    u16x8 vr0 = *(const u16x8*)(vbase + (size_t)srow * SL + scol);
    u16x8 vr1 = *(const u16x8*)(vbase + (size_t)srow * SL + scol + 8);

    for (int t = 0; t <= tmax; ++t) {
        const int s0 = t * KBLK;
        __syncthreads();
        {
            u32x4 a0 = {pk2(kf[0][0], kf[0][1]), pk2(kf[0][2], kf[0][3]),
                        pk2(kf[1][0], kf[1][1]), pk2(kf[1][2], kf[1][3])};
            u32x4 a1 = {pk2(kf[2][0], kf[2][1]), pk2(kf[2][2], kf[2][3]),
                        pk2(kf[3][0], kf[3][1]), pk2(kf[3][2], kf[3][3])};
            *(u16x8*)&Klds[srow * PAD + scol]     = __builtin_bit_cast(u16x8, a0);
            *(u16x8*)&Klds[srow * PAD + scol + 8] = __builtin_bit_cast(u16x8, a1);
            *(u16x8*)&Vlds[srow * PAD + scol]     = vr0;
            *(u16x8*)&Vlds[srow * PAD + scol + 8] = vr1;
        }
        if (t < tmax) {
            const int s1 = s0 + KBLK;
            #pragma unroll
            for (int j = 0; j < 4; ++j)
                kf[j] = *(const f32x4*)(kgbase + (size_t)(s1 + srow) * NH * HD + scol + j * 4);
            vr0 = *(const u16x8*)(vbase + (size_t)srow * SL + s1 + scol);
            vr1 = *(const u16x8*)(vbase + (size_t)srow * SL + s1 + scol + 8);
        }
        __syncthreads();

        bool act[2];
        #pragma unroll
        for (int fi = 0; fi < 2; ++fi) act[fi] = (s0 <= qrows[fi] + 31);

        // K fragments (A operand): lane holds K[s0 + ms*32 + l31][e = kk*16 + hi*8 + j]
        bf16x8 kfr[2][4];
        #pragma unroll
        for (int ms = 0; ms < 2; ++ms)
            #pragma unroll
            for (int kk = 0; kk < 4; ++kk)
                kfr[ms][kk] = __builtin_bit_cast(bf16x8,
                    *(u16x8*)&Klds[(ms * 32 + l31) * PAD + kk * 16 + hi * 8]);

        // ---- stage 1: QK^T for BOTH fi (MFMAs issue back-to-back) ----
        f32x16 sacc[2][2];
        #pragma unroll
        for (int fi = 0; fi < 2; ++fi) {
            if (!act[fi]) continue;
            #pragma unroll
            for (int ms = 0; ms < 2; ++ms) {
                f32x16 c;
                #pragma unroll
                for (int r = 0; r < 16; ++r) c[r] = 0.f;
                #pragma unroll
                for (int kk = 0; kk < 4; ++kk)
                    c = __builtin_amdgcn_mfma_f32_32x32x16_bf16(kfr[ms][kk], qfrag[fi][kk], c, 0, 0, 0);
                sacc[fi][ms] = c;
            }
        }

        // ---- stage 2: softmax + P-exchange for BOTH fi (two independent
        //      VALU chains -> scheduler can interleave them) ----
        bf16x8 pfr[2][4];
        #pragma unroll
        for (int fi = 0; fi < 2; ++fi) {
            if (!act[fi]) continue;
            const int qf = qrows[fi];

            // causal mask: s > q  (gate: any s in tile exceeds the wave's min q)
            if (s0 + KBLK - 1 > qf) {
                const int q = qf + l31;
                #pragma unroll
                for (int ms = 0; ms < 2; ++ms)
                    #pragma unroll
                    for (int r = 0; r < 16; ++r) {
                        const int s = s0 + ms * 32 + (r & 3) + 8 * (r >> 2) + 4 * hi;
                        if (s > q) sacc[fi][ms][r] = -1e30f;
                    }
            }

            // per-lane PARTIAL max over 32 values (tree); lazy cross-lane via __all
            float u[16];
            #pragma unroll
            for (int i = 0; i < 8; ++i) u[i]     = fmaxf(sacc[fi][0][2 * i], sacc[fi][0][2 * i + 1]);
            #pragma unroll
            for (int i = 0; i < 8; ++i) u[8 + i] = fmaxf(sacc[fi][1][2 * i], sacc[fi][1][2 * i + 1]);
            #pragma unroll
            for (int st = 8; st >= 1; st >>= 1)
                #pragma unroll
                for (int i = 0; i < 16; ++i)
                    if (i < st) u[i] = fmaxf(u[i], u[i + st]);
            const float pp = u[0];

            if (!__all(pp - m_run[fi] <= 8.0f)) {
                float pmax = fmaxf(pp, __shfl_xor(pp, 32, 64));
                const float mnew = fmaxf(m_run[fi], pmax);
                const float alpha = fexp2(m_run[fi] - mnew);
                m_run[fi] = mnew;
                l_run[fi] *= alpha;
                #pragma unroll
                for (int d = 0; d < 2; ++d)
                    #pragma unroll
                    for (int r = 0; r < 16; ++r) oacc[fi][d][r] *= alpha;
            }

            // P = 2^(S-m); per-lane partial row-sum (tree)
            #pragma unroll
            for (int ms = 0; ms < 2; ++ms)
                #pragma unroll
                for (int r = 0; r < 16; ++r)
                    sacc[fi][ms][r] = fexp2(sacc[fi][ms][r] - m_run[fi]);
            {
                float sv[16];
                #pragma unroll
                for (int i = 0; i < 8; ++i) sv[i]     = sacc[fi][0][2 * i] + sacc[fi][0][2 * i + 1];
                #pragma unroll
                for (int i = 0; i < 8; ++i) sv[8 + i] = sacc[fi][1][2 * i] + sacc[fi][1][2 * i + 1];
                #pragma unroll
                for (int st = 8; st >= 1; st >>= 1)
                    #pragma unroll
                    for (int i = 0; i < 16; ++i)
                        if (i < st) sv[i] += sv[i + st];
                l_run[fi] += sv[0];
            }

            // P exchange -> B-operand fragments (one pl32swap per word-pair)
            #pragma unroll
            for (int ms = 0; ms < 2; ++ms) {
                unsigned Y0[4], Y1[4];
                #pragma unroll
                for (int k = 0; k < 4; ++k) {
                    Y0[k] = pk2(sacc[fi][ms][4 * k + 0], sacc[fi][ms][4 * k + 1]);
                    Y1[k] = pk2(sacc[fi][ms][4 * k + 2], sacc[fi][ms][4 * k + 3]);
                }
                #pragma unroll
                for (int c = 0; c < 2; ++c) {
                    unsigned X0 = Y0[2 * c], Z0 = Y0[2 * c + 1];
                    unsigned X1 = Y1[2 * c], Z1 = Y1[2 * c + 1];
                    pl32swap(X0, Z0);
                    pl32swap(X1, Z1);
                    u32x4 wv = {X0, X1, Z0, Z1};
                    pfr[fi][ms * 2 + c] = __builtin_bit_cast(bf16x8, wv);
                }
            }
        }

        // ---- stage 3: PV for both fi; V-frags (A operand) shared ----
        #pragma unroll
        for (int dsub = 0; dsub < 2; ++dsub) {
            bf16x8 vf[4];
            #pragma unroll
            for (int sc = 0; sc < 4; ++sc)
                vf[sc] = __builtin_bit_cast(bf16x8,
                    *(u16x8*)&Vlds[(dsub * 32 + l31) * PAD + sc * 16 + hi * 8]);
            #pragma unroll
            for (int fi = 0; fi < 2; ++fi) {
                if (!act[fi]) continue;
                #pragma unroll
                for (int sc = 0; sc < 4; ++sc)
                    oacc[fi][dsub] = __builtin_amdgcn_mfma_f32_32x32x16_bf16(
                        vf[sc], pfr[fi][sc], oacc[fi][dsub], 0, 0, 0);
            }
        }
    }

    // epilogue: lane owns q-row qf+l31; d = dsub*32 + 8*(r>>2) + 4*hi + (r&3)
    #pragma unroll
    for (int fi = 0; fi < 2; ++fi) {
        float lt = l_run[fi];
        lt += __shfl_xor(lt, 32, 64);
        const float inv = 1.0f / lt;
        float* op = Og + ((size_t)(b * SL + qrows[fi] + l31) * NH + h) * HD + 4 * hi;
        #pragma unroll
        for (int dsub = 0; dsub < 2; ++dsub)
            #pragma unroll
            for (int q2 = 0; q2 < 4; ++q2) {
                f32x4 o = {oacc[fi][dsub][4 * q2 + 0] * inv,
                           oacc[fi][dsub][4 * q2 + 1] * inv,
                           oacc[fi][dsub][4 * q2 + 2] * inv,
                           oacc[fi][dsub][4 * q2 + 3] * inv};
                *(f32x4*)(op + dsub * 32 + 8 * q2) = o;
            }
    }
}

extern "C" void kernel_launch(void* const* d_in, const int* in_sizes, int n_in,
                              void* d_out, int out_size, void* d_ws, size_t ws_size,
                              hipStream_t stream) {
    const float* Qg = (const float*)d_in[0];
    const float* Kg = (const float*)d_in[1];
    const float* Vg = (const float*)d_in[2];
    float* Og = (float*)d_out;

    const size_t elems = (size_t)NB * NH * SL * HD;
    if (ws_size < elems * sizeof(unsigned short)) return;
    unsigned short* Vtb = (unsigned short*)d_ws;

    hipLaunchKernelGGL(conv_v, dim3(NB * NH * (SL / 64)), dim3(256), 0, stream, Vg, Vtb);
    hipLaunchKernelGGL(fattn_kernel, dim3(8 * 64), dim3(256), 0, stream,
                       Qg, Kg, Vtb, Og);
}

// Round 22
// 74.279 us; speedup vs baseline: 1.3764x; 1.3764x over previous
//
#include <hip/hip_runtime.h>
#include <hip/hip_bf16.h>

typedef float f32x4 __attribute__((ext_vector_type(4)));
typedef float f32x16 __attribute__((ext_vector_type(16)));
typedef __bf16 bf16x8 __attribute__((ext_vector_type(8)));
typedef unsigned short u16x8 __attribute__((ext_vector_type(8)));
typedef unsigned u32x4 __attribute__((ext_vector_type(4)));

#define NB 4
#define SL 2048
#define NH 16
#define HD 64
#define KBLK 64
#define PAD 72
#define NT 16            // q-tiles of 128

static __device__ __forceinline__ unsigned short f2bf(float f) {
    unsigned u = __builtin_bit_cast(unsigned, f);
    u += 0x7fffu + ((u >> 16) & 1u);
    return (unsigned short)(u >> 16);
}

static __device__ __forceinline__ unsigned pk2(float lo, float hi) {
    unsigned r;
    asm("v_cvt_pk_bf16_f32 %0, %1, %2" : "=v"(r) : "v"(lo), "v"(hi));
    return r;
}

// raw 2^x (args <= 8 here; -1e30 -> 0 as desired)
static __device__ __forceinline__ float fexp2(float x) {
    float r;
    asm("v_exp_f32 %0, %1" : "=v"(r) : "v"(x));
    return r;
}

// a' = [a.lo32 | b.lo32], b' = [a.hi32 | b.hi32]  (r7-proven semantics)
static __device__ __forceinline__ void pl32swap(unsigned& a, unsigned& b) {
    asm("v_permlane32_swap_b32 %0, %1" : "+v"(a), "+v"(b));
}

// ---- prologue: V fp32 [b][s][h][d] -> bf16 transposed [b][h][d][s] ----
__global__ void conv_v(const float* __restrict__ Vg, unsigned short* __restrict__ Vtb) {
    __shared__ unsigned short T[64 * PAD];
    const int tid = threadIdx.x;
    const int id  = blockIdx.x;
    const int st  = id & 31;
    const int bh  = id >> 5;
    const int s0  = st * 64;
    {
        const int sl = tid >> 2, c = (tid & 3) * 16;
        const float* src = Vg + ((size_t)((bh >> 4) * SL + s0 + sl) * NH + (bh & 15)) * HD + c;
        u16x8 a, b2;
        #pragma unroll
        for (int j = 0; j < 8; ++j) { a[j] = f2bf(src[j]); b2[j] = f2bf(src[8 + j]); }
        *(u16x8*)&T[sl * PAD + c]     = a;
        *(u16x8*)&T[sl * PAD + c + 8] = b2;
    }
    __syncthreads();
    {
        const int d = tid >> 2, sc = (tid & 3) * 16;
        u16x8 o0, o1;
        #pragma unroll
        for (int j = 0; j < 8; ++j) { o0[j] = T[(sc + j) * PAD + d]; o1[j] = T[(sc + 8 + j) * PAD + d]; }
        unsigned short* dst = Vtb + ((size_t)bh * HD + d) * SL + s0 + sc;
        *(u16x8*)dst       = o0;
        *(u16x8*)(dst + 8) = o1;
    }
}

// ---- main: 4 waves/block, 2 fi/wave of 32 q-rows, 32x32x16 MFMA ----
__global__ __launch_bounds__(256, 2)
void fattn_kernel(const float* __restrict__ Qg, const float* __restrict__ Kg,
                  const unsigned short* __restrict__ Vtb, float* __restrict__ Og)
{
    __shared__ unsigned short Klds[KBLK * PAD];
    __shared__ unsigned short Vlds[HD * PAD];

    const int tid  = threadIdx.x;
    const int w    = tid >> 6;          // 0..3
    const int lane = tid & 63;
    const int l31  = lane & 31;
    const int hi   = lane >> 5;

    const int bh   = blockIdx.x & 63;
    const int rawp = blockIdx.x >> 6;   // 0..7
    const int p    = (rawp < 4) ? rawp : 11 - rawp;
    const int b    = bh >> 4;
    const int h    = bh & 15;

    int qrows[2];
    qrows[0] = p * 128 + w * 32;              // tile p (short)
    qrows[1] = (NT - 1 - p) * 128 + w * 32;   // tile 15-p (long)
    const int tmax = 2 * (NT - 1 - p) + 1;

    const float QSCALE = 0.125f * 1.44269504088896f;  // (1/sqrt64)*log2(e)
    // Q-frag (B operand): lane holds Q[qf+l31][e = kk*16 + hi*8 + j]
    bf16x8 qfrag[2][4];
    #pragma unroll
    for (int fi = 0; fi < 2; ++fi) {
        const int q = qrows[fi] + l31;
        const float* qp = Qg + ((size_t)(b * SL + q) * NH + h) * HD + hi * 8;
        #pragma unroll
        for (int kk = 0; kk < 4; ++kk) {
            f32x4 a = *(const f32x4*)(qp + kk * 16);
            f32x4 b2 = *(const f32x4*)(qp + kk * 16 + 4);
            u16x8 t;
            #pragma unroll
            for (int j = 0; j < 4; ++j) { t[j] = f2bf(a[j] * QSCALE); t[4 + j] = f2bf(b2[j] * QSCALE); }
            qfrag[fi][kk] = __builtin_bit_cast(bf16x8, t);
        }
    }

    float m_run[2] = {-1e30f, -1e30f};
    float l_run[2] = {0.f, 0.f};   // per-lane partials, reduced at epilogue
    f32x16 oacc[2][2];             // [fi][dsub]
    #pragma unroll
    for (int fi = 0; fi < 2; ++fi)
        #pragma unroll
        for (int d = 0; d < 2; ++d)
            #pragma unroll
            for (int r = 0; r < 16; ++r) oacc[fi][d][r] = 0.f;

    const int srow = tid >> 2;          // 0..63
    const int scol = (tid & 3) * 16;    // 0..48
    const float* kgbase = Kg + ((size_t)b * SL * NH + h) * HD;
    const unsigned short* vbase = Vtb + (size_t)bh * HD * SL;

    f32x4 kf[4];
    #pragma unroll
    for (int j = 0; j < 4; ++j)
        kf[j] = *(const f32x4*)(kgbase + (size_t)srow * NH * HD + scol + j * 4);
    u16x8 vr0 = *(const u16x8*)(vbase + (size_t)srow * SL + scol);
    u16x8 vr1 = *(const u16x8*)(vbase + (size_t)srow * SL + scol + 8);

    for (int t = 0; t <= tmax; ++t) {
        const int s0 = t * KBLK;
        __syncthreads();
        {
            u32x4 a0 = {pk2(kf[0][0], kf[0][1]), pk2(kf[0][2], kf[0][3]),
                        pk2(kf[1][0], kf[1][1]), pk2(kf[1][2], kf[1][3])};
            u32x4 a1 = {pk2(kf[2][0], kf[2][1]), pk2(kf[2][2], kf[2][3]),
                        pk2(kf[3][0], kf[3][1]), pk2(kf[3][2], kf[3][3])};
            *(u16x8*)&Klds[srow * PAD + scol]     = __builtin_bit_cast(u16x8, a0);
            *(u16x8*)&Klds[srow * PAD + scol + 8] = __builtin_bit_cast(u16x8, a1);
            *(u16x8*)&Vlds[srow * PAD + scol]     = vr0;
            *(u16x8*)&Vlds[srow * PAD + scol + 8] = vr1;
        }
        if (t < tmax) {
            const int s1 = s0 + KBLK;
            #pragma unroll
            for (int j = 0; j < 4; ++j)
                kf[j] = *(const f32x4*)(kgbase + (size_t)(s1 + srow) * NH * HD + scol + j * 4);
            vr0 = *(const u16x8*)(vbase + (size_t)srow * SL + s1 + scol);
            vr1 = *(const u16x8*)(vbase + (size_t)srow * SL + s1 + scol + 8);
        }
        __syncthreads();

        bool act[2];
        #pragma unroll
        for (int fi = 0; fi < 2; ++fi) act[fi] = (s0 <= qrows[fi] + 31);

        // K fragments (A operand): lane holds K[s0 + ms*32 + l31][e = kk*16 + hi*8 + j]
        bf16x8 kfr[2][4];
        #pragma unroll
        for (int ms = 0; ms < 2; ++ms)
            #pragma unroll
            for (int kk = 0; kk < 4; ++kk)
                kfr[ms][kk] = __builtin_bit_cast(bf16x8,
                    *(u16x8*)&Klds[(ms * 32 + l31) * PAD + kk * 16 + hi * 8]);

        bf16x8 pfr[2][4];
        #pragma unroll
        for (int fi = 0; fi < 2; ++fi) {
            if (!act[fi]) continue;
            const int qf = qrows[fi];

            // S^T = K Q^T : lane owns col q=qf+l31; rows per reg r:
            // s = s0 + ms*32 + (r&3) + 8*(r>>2) + 4*hi
            f32x16 sacc[2];
            #pragma unroll
            for (int ms = 0; ms < 2; ++ms) {
                f32x16 c;
                #pragma unroll
                for (int r = 0; r < 16; ++r) c[r] = 0.f;
                #pragma unroll
                for (int kk = 0; kk < 4; ++kk)
                    c = __builtin_amdgcn_mfma_f32_32x32x16_bf16(kfr[ms][kk], qfrag[fi][kk], c, 0, 0, 0);
                sacc[ms] = c;
            }

            // causal mask: s > q  (gate: any s in tile exceeds the wave's min q)
            if (s0 + KBLK - 1 > qf) {
                const int q = qf + l31;
                #pragma unroll
                for (int ms = 0; ms < 2; ++ms)
                    #pragma unroll
                    for (int r = 0; r < 16; ++r) {
                        const int s = s0 + ms * 32 + (r & 3) + 8 * (r >> 2) + 4 * hi;
                        if (s > q) sacc[ms][r] = -1e30f;
                    }
            }

            // per-lane PARTIAL max over 32 values (tree); lazy cross-lane via __all
            float u[16];
            #pragma unroll
            for (int i = 0; i < 8; ++i) u[i]     = fmaxf(sacc[0][2 * i], sacc[0][2 * i + 1]);
            #pragma unroll
            for (int i = 0; i < 8; ++i) u[8 + i] = fmaxf(sacc[1][2 * i], sacc[1][2 * i + 1]);
            #pragma unroll
            for (int st = 8; st >= 1; st >>= 1)
                #pragma unroll
                for (int i = 0; i < 16; ++i)
                    if (i < st) u[i] = fmaxf(u[i], u[i + st]);
            const float pp = u[0];

            if (!__all(pp - m_run[fi] <= 8.0f)) {
                float pmax = fmaxf(pp, __shfl_xor(pp, 32, 64));
                const float mnew = fmaxf(m_run[fi], pmax);
                const float alpha = fexp2(m_run[fi] - mnew);
                m_run[fi] = mnew;
                l_run[fi] *= alpha;
                #pragma unroll
                for (int d = 0; d < 2; ++d)
                    #pragma unroll
                    for (int r = 0; r < 16; ++r) oacc[fi][d][r] *= alpha;
            }

            // P = 2^(S-m); per-lane partial row-sum (tree)
            #pragma unroll
            for (int ms = 0; ms < 2; ++ms)
                #pragma unroll
                for (int r = 0; r < 16; ++r)
                    sacc[ms][r] = fexp2(sacc[ms][r] - m_run[fi]);
            {
                float sv[16];
                #pragma unroll
                for (int i = 0; i < 8; ++i) sv[i]     = sacc[0][2 * i] + sacc[0][2 * i + 1];
                #pragma unroll
                for (int i = 0; i < 8; ++i) sv[8 + i] = sacc[1][2 * i] + sacc[1][2 * i + 1];
                #pragma unroll
                for (int st = 8; st >= 1; st >>= 1)
                    #pragma unroll
                    for (int i = 0; i < 16; ++i)
                        if (i < st) sv[i] += sv[i + st];
                l_run[fi] += sv[0];
            }

            // P exchange -> B-operand fragments (one pl32swap per word-pair):
            // quad k covers rows 8k + 4*hi + {0..3}; chunk c needs quads 2c, 2c+1.
            // After swap(X=Y[2c][w], Z=Y[2c+1][w]): chunk words = [X'0, X'1, Z'0, Z'1].
            #pragma unroll
            for (int ms = 0; ms < 2; ++ms) {
                unsigned Y0[4], Y1[4];
                #pragma unroll
                for (int k = 0; k < 4; ++k) {
                    Y0[k] = pk2(sacc[ms][4 * k + 0], sacc[ms][4 * k + 1]);
                    Y1[k] = pk2(sacc[ms][4 * k + 2], sacc[ms][4 * k + 3]);
                }
                #pragma unroll
                for (int c = 0; c < 2; ++c) {
                    unsigned X0 = Y0[2 * c], Z0 = Y0[2 * c + 1];
                    unsigned X1 = Y1[2 * c], Z1 = Y1[2 * c + 1];
                    pl32swap(X0, Z0);
                    pl32swap(X1, Z1);
                    u32x4 wv = {X0, X1, Z0, Z1};
                    pfr[fi][ms * 2 + c] = __builtin_bit_cast(bf16x8, wv);
                }
            }
        }

        // PV: oacc += V^T x P ; V-frags (A operand) shared across both fi
        #pragma unroll
        for (int dsub = 0; dsub < 2; ++dsub) {
            bf16x8 vf[4];
            #pragma unroll
            for (int sc = 0; sc < 4; ++sc)
                vf[sc] = __builtin_bit_cast(bf16x8,
                    *(u16x8*)&Vlds[(dsub * 32 + l31) * PAD + sc * 16 + hi * 8]);
            #pragma unroll
            for (int fi = 0; fi < 2; ++fi) {
                if (!act[fi]) continue;
                #pragma unroll
                for (int sc = 0; sc < 4; ++sc)
                    oacc[fi][dsub] = __builtin_amdgcn_mfma_f32_32x32x16_bf16(
                        vf[sc], pfr[fi][sc], oacc[fi][dsub], 0, 0, 0);
            }
        }
    }

    // epilogue: lane owns q-row qf+l31; d = dsub*32 + 8*(r>>2) + 4*hi + (r&3)
    #pragma unroll
    for (int fi = 0; fi < 2; ++fi) {
        float lt = l_run[fi];
        lt += __shfl_xor(lt, 32, 64);
        const float inv = 1.0f / lt;
        float* op = Og + ((size_t)(b * SL + qrows[fi] + l31) * NH + h) * HD + 4 * hi;
        #pragma unroll
        for (int dsub = 0; dsub < 2; ++dsub)
            #pragma unroll
            for (int q2 = 0; q2 < 4; ++q2) {
                f32x4 o = {oacc[fi][dsub][4 * q2 + 0] * inv,
                           oacc[fi][dsub][4 * q2 + 1] * inv,
                           oacc[fi][dsub][4 * q2 + 2] * inv,
                           oacc[fi][dsub][4 * q2 + 3] * inv};
                *(f32x4*)(op + dsub * 32 + 8 * q2) = o;
            }
    }
}

extern "C" void kernel_launch(void* const* d_in, const int* in_sizes, int n_in,
                              void* d_out, int out_size, void* d_ws, size_t ws_size,
                              hipStream_t stream) {
    const float* Qg = (const float*)d_in[0];
    const float* Kg = (const float*)d_in[1];
    const float* Vg = (const float*)d_in[2];
    float* Og = (float*)d_out;

    const size_t elems = (size_t)NB * NH * SL * HD;
    if (ws_size < elems * sizeof(unsigned short)) return;
    unsigned short* Vtb = (unsigned short*)d_ws;

    hipLaunchKernelGGL(conv_v, dim3(NB * NH * (SL / 64)), dim3(256), 0, stream, Vg, Vtb);
    hipLaunchKernelGGL(fattn_kernel, dim3(8 * 64), dim3(256), 0, stream,
                       Qg, Kg, Vtb, Og);
}